// Round 1
// baseline (5278.288 us; speedup 1.0000x reference)
//
#include <hip/hip_runtime.h>
#include <cstddef>

#define Tn 512
#define Bn 32
#define Hn 512
#define BTn 16384
static const size_t PLANE = 8388608; // Bn*Tn*Hn = 32*512*512

__device__ __forceinline__ float sigm(float x) { return 1.0f / (1.0f + __expf(-x)); }
__device__ __forceinline__ float tanh_fast(float x) { return 2.0f / (1.0f + __expf(-2.0f * x)) - 1.0f; }

// C[m=(g,o), n=(b,t)] = sum_k W[m,k] * A[n,k],  k = c*2 + tap (matches w layout [o][c][k])
// A[n, (c,tap)] = X[b, trow(t,tap), c];  trow = (dir==0) ? t-1+tap : T-t-tap ; zero outside [0,T)
// Output written as gates[g][n][o] (n-major, o contiguous) for scan-kernel coalescing.
__global__ __launch_bounds__(256) void gate_gemm(
    const float* __restrict__ X, const float* __restrict__ W,
    float* __restrict__ gates, int Kdim, long long sB, long long sT, int dir)
{
    __shared__ float Ws[16][128];
    __shared__ float Xs[16][128];
    const int tid = threadIdx.x;
    const int tx = tid & 15;
    const int ty = tid >> 4;
    const int n0 = blockIdx.x * 128;
    const int m0 = blockIdx.y * 128;

    // loader assignment: each thread loads 8 floats of W-row (m=tid/2, k-half=tid&1)
    // and 8 channel-floats of one X-row (n=tid/2, tap=tid&1)
    const int lm = tid >> 1;
    const int lhalf = tid & 1;
    const int ln = tid >> 1;
    const int ltap = tid & 1;

    const int n_l = n0 + ln;
    const int t_l = n_l & (Tn - 1);
    const int b_l = n_l >> 9;
    const int trow = (dir == 0) ? (t_l - 1 + ltap) : (Tn - t_l - ltap);
    const bool valid = (trow >= 0) && (trow < Tn);
    const float* xrow = X + (long long)b_l * sB + (long long)trow * sT;
    const float* wrow = W + (long long)(m0 + lm) * Kdim + lhalf * 8;

    float acc[8][8];
#pragma unroll
    for (int i = 0; i < 8; ++i)
#pragma unroll
        for (int j = 0; j < 8; ++j) acc[i][j] = 0.0f;

    const int KT = Kdim >> 4;
    for (int kt = 0; kt < KT; ++kt) {
        const int k0 = kt << 4;  // k offset
        const int c0 = kt << 3;  // channel offset
        float4 wv0 = *(const float4*)(wrow + k0);
        float4 wv1 = *(const float4*)(wrow + k0 + 4);
        float4 xv0 = make_float4(0.f, 0.f, 0.f, 0.f);
        float4 xv1 = make_float4(0.f, 0.f, 0.f, 0.f);
        if (valid) {
            xv0 = *(const float4*)(xrow + c0);
            xv1 = *(const float4*)(xrow + c0 + 4);
        }
        Ws[lhalf * 8 + 0][lm] = wv0.x;
        Ws[lhalf * 8 + 1][lm] = wv0.y;
        Ws[lhalf * 8 + 2][lm] = wv0.z;
        Ws[lhalf * 8 + 3][lm] = wv0.w;
        Ws[lhalf * 8 + 4][lm] = wv1.x;
        Ws[lhalf * 8 + 5][lm] = wv1.y;
        Ws[lhalf * 8 + 6][lm] = wv1.z;
        Ws[lhalf * 8 + 7][lm] = wv1.w;
        // k = (c0+e)*2 + tap  -> local row e*2+tap
        Xs[0 + ltap][ln] = xv0.x;
        Xs[2 + ltap][ln] = xv0.y;
        Xs[4 + ltap][ln] = xv0.z;
        Xs[6 + ltap][ln] = xv0.w;
        Xs[8 + ltap][ln] = xv1.x;
        Xs[10 + ltap][ln] = xv1.y;
        Xs[12 + ltap][ln] = xv1.z;
        Xs[14 + ltap][ln] = xv1.w;
        __syncthreads();
#pragma unroll
        for (int kk = 0; kk < 16; ++kk) {
            float av[8], bv[8];
            *(float4*)&av[0] = *(const float4*)&Ws[kk][ty * 8];
            *(float4*)&av[4] = *(const float4*)&Ws[kk][ty * 8 + 4];
            *(float4*)&bv[0] = *(const float4*)&Xs[kk][tx * 8];
            *(float4*)&bv[4] = *(const float4*)&Xs[kk][tx * 8 + 4];
#pragma unroll
            for (int i = 0; i < 8; ++i)
#pragma unroll
                for (int j = 0; j < 8; ++j)
                    acc[i][j] += av[i] * bv[j];
        }
        __syncthreads();
    }

    // epilogue: m = m0 + ty*8 + i -> g = m>>9 (constant per block), o = m&511
    const int g = m0 >> 9;
    const int o0 = (m0 & 511) + ty * 8;
    float* gbase = gates + (size_t)g * PLANE;
#pragma unroll
    for (int j = 0; j < 8; ++j) {
        const int n = n0 + tx * 8 + j;
        float4 v0 = make_float4(acc[0][j], acc[1][j], acc[2][j], acc[3][j]);
        float4 v1 = make_float4(acc[4][j], acc[5][j], acc[6][j], acc[7][j]);
        float* p = gbase + (size_t)n * Hn + o0;
        *(float4*)p = v0;
        *(float4*)(p + 4) = v1;
    }
}

// Phase A: per (b,o,chunk): activate gates (f := sigmoid(f+bf) in place, i := sigm(i+bi)*tanh(z+bz)
// in place), accumulate chunk composition (F = prod f, S = chunk applied to c=0).
__global__ __launch_bounds__(256) void scan_A(
    float* __restrict__ gates, const float* __restrict__ bias,
    float* __restrict__ Fsum, float* __restrict__ Ssum)
{
    const int idx = blockIdx.x * 256 + threadIdx.x; // 131072 = 8 chunks * 32 b * 512 o
    const int o = idx & 511;
    const int b = (idx >> 9) & 31;
    const int chunk = idx >> 14;
    const float bz = bias[o];
    const float bf = bias[512 + o];
    const float bi = bias[1536 + o];
    float F = 1.0f, S = 0.0f;
    const int tbase = chunk * 64;
    for (int tt = 0; tt < 64; ++tt) {
        const size_t idxg = ((size_t)(b * 512 + tbase + tt)) * 512 + o;
        const float zp = gates[idxg] + bz;
        const float fp = gates[PLANE + idxg] + bf;
        const float ip = gates[3 * PLANE + idxg] + bi;
        const float f = sigm(fp);
        const float iz = sigm(ip) * tanh_fast(zp);
        gates[PLANE + idxg] = f;
        gates[3 * PLANE + idxg] = iz;
        F *= f;
        S = f * S + iz;
    }
    Fsum[idx] = F;
    Ssum[idx] = S;
}

// Phase B: per (b,o): compose the 8 chunk summaries -> per-chunk starting c.
__global__ __launch_bounds__(256) void scan_B(
    const float* __restrict__ Fsum, const float* __restrict__ Ssum,
    float* __restrict__ cstart)
{
    const int i = blockIdx.x * 256 + threadIdx.x; // 16384
    float c = 0.0f;
    for (int ch = 0; ch < 8; ++ch) {
        cstart[ch * 16384 + i] = c;
        c = Fsum[ch * 16384 + i] * c + Ssum[ch * 16384 + i];
    }
}

// Phase C: per (b,o,chunk): redo recurrence from cstart, emit out = sigm(o_pre+bo)*c.
// isLayer2: write to final output layout (T,B,2H); else h1 layout (B,T,2H).
// h_n entry: d==0 -> t==T-2 ; d==1 -> t==0 (reversed frame).
__global__ __launch_bounds__(256) void scan_C(
    const float* __restrict__ gates, const float* __restrict__ bias,
    const float* __restrict__ cstart, float* __restrict__ dst,
    float* __restrict__ hn, int isLayer2, int dirH)
{
    const int idx = blockIdx.x * 256 + threadIdx.x;
    const int o = idx & 511;
    const int b = (idx >> 9) & 31;
    const int chunk = idx >> 14;
    const float bo_ = bias[1024 + o];
    float c = cstart[idx];
    const int tbase = chunk * 64;
    for (int tt = 0; tt < 64; ++tt) {
        const int t = tbase + tt;
        const size_t idxg = ((size_t)(b * 512 + t)) * 512 + o;
        const float f = gates[PLANE + idxg];
        const float iz = gates[3 * PLANE + idxg];
        const float op = gates[2 * PLANE + idxg] + bo_;
        c = f * c + iz;
        const float out = sigm(op) * c;
        if (isLayer2) {
            dst[((size_t)t * Bn + b) * 1024 + dirH + o] = out;
        } else {
            dst[((size_t)b * Tn + t) * 1024 + dirH + o] = out;
        }
        const bool isLast = (dirH == 0) ? (t == Tn - 2) : (t == 0);
        if (isLast) {
            hn[(size_t)b * 1024 + dirH + o] = out;
        }
    }
}

extern "C" void kernel_launch(void* const* d_in, const int* in_sizes, int n_in,
                              void* d_out, int out_size, void* d_ws, size_t ws_size,
                              hipStream_t stream) {
    const float* x  = (const float*)d_in[0];   // (T,B,C)
    const float* w0 = (const float*)d_in[1];   // (2,4,H,C,2)
    const float* b0 = (const float*)d_in[2];   // (2,4,H)
    const float* w1 = (const float*)d_in[3];   // (2,4,H,2H,2)
    const float* b1 = (const float*)d_in[4];   // (2,4,H)
    float* out = (float*)d_out;                // output (T,B,2H) then h_n (2,B,2H)
    float* ws = (float*)d_ws;

    float* gates = ws;                         // 4 * PLANE floats = 134.2 MB
    float* h1    = gates + 4 * PLANE;          // (B,T,2H) = 16777216 floats
    float* Fsum  = h1 + 16777216;              // 131072
    float* Ssum  = Fsum + 131072;              // 131072
    float* cst   = Ssum + 131072;              // 131072
    float* hn    = out + 16777216;             // h_n part of d_out

    const dim3 gg(128, 16);

    // ---- Layer 1, forward ----
    gate_gemm<<<gg, 256, 0, stream>>>(x, w0, gates, 1024, 512LL, 16384LL, 0);
    scan_A<<<512, 256, 0, stream>>>(gates, b0, Fsum, Ssum);
    scan_B<<<64, 256, 0, stream>>>(Fsum, Ssum, cst);
    scan_C<<<512, 256, 0, stream>>>(gates, b0, cst, h1, hn, 0, 0);
    // ---- Layer 1, reverse ----
    gate_gemm<<<gg, 256, 0, stream>>>(x, w0 + 2097152, gates, 1024, 512LL, 16384LL, 1);
    scan_A<<<512, 256, 0, stream>>>(gates, b0 + 2048, Fsum, Ssum);
    scan_B<<<64, 256, 0, stream>>>(Fsum, Ssum, cst);
    scan_C<<<512, 256, 0, stream>>>(gates, b0 + 2048, cst, h1, hn, 0, 512);
    // ---- Layer 2, forward ----
    gate_gemm<<<gg, 256, 0, stream>>>(h1, w1, gates, 2048, 524288LL, 1024LL, 0);
    scan_A<<<512, 256, 0, stream>>>(gates, b1, Fsum, Ssum);
    scan_B<<<64, 256, 0, stream>>>(Fsum, Ssum, cst);
    scan_C<<<512, 256, 0, stream>>>(gates, b1, cst, out, hn + 32768, 1, 0);
    // ---- Layer 2, reverse ----
    gate_gemm<<<gg, 256, 0, stream>>>(h1, w1 + 4194304, gates, 2048, 524288LL, 1024LL, 1);
    scan_A<<<512, 256, 0, stream>>>(gates, b1 + 2048, Fsum, Ssum);
    scan_B<<<64, 256, 0, stream>>>(Fsum, Ssum, cst);
    scan_C<<<512, 256, 0, stream>>>(gates, b1 + 2048, cst, out, hn + 32768, 1, 512);
}

// Round 2
// 969.913 us; speedup vs baseline: 5.4420x; 5.4420x over previous
//
#include <hip/hip_runtime.h>
#include <cstddef>
#include <cstdint>

#define Tn 512
#define Bn 32
#define Hn 512
static const size_t PLANE = 8388608; // Bn*Tn*Hn

typedef float f32x4 __attribute__((ext_vector_type(4)));
typedef __bf16 bf16x8 __attribute__((ext_vector_type(8)));

__device__ __forceinline__ float sigm(float x) { return 1.0f / (1.0f + __expf(-x)); }
__device__ __forceinline__ float tanh_fast(float x) { return 2.0f / (1.0f + __expf(-2.0f * x)) - 1.0f; }
__device__ __forceinline__ unsigned short f2bf(float f) {
    unsigned int u = __float_as_uint(f);
    u += 0x7FFF + ((u >> 16) & 1);   // RNE
    return (unsigned short)(u >> 16);
}
__device__ __forceinline__ void gload16(const void* g, void* l) {
    __builtin_amdgcn_global_load_lds(
        (const __attribute__((address_space(1))) unsigned int*)g,
        (__attribute__((address_space(3))) unsigned int*)l, 16, 0, 0);
}

// ---------------- conversion kernels ----------------

// x (T,B,C) fp32 -> xbf [b][t+1][c] bf16 with zero rows at tp=0 and tp=513
__global__ __launch_bounds__(256) void conv_x(const float* __restrict__ x,
                                              unsigned short* __restrict__ xbf) {
    const int i = blockIdx.x * 256 + threadIdx.x;  // 32*514*64
    const int c8 = i & 63;
    const int tp = (i >> 6) % 514;
    const int b  = (i >> 6) / 514;
    unsigned short v[8];
    if (tp == 0 || tp == 513) {
#pragma unroll
        for (int j = 0; j < 8; ++j) v[j] = 0;
    } else {
        const float* s = x + ((size_t)(tp - 1) * Bn + b) * 512 + c8 * 8;
#pragma unroll
        for (int j = 0; j < 8; ++j) v[j] = f2bf(s[j]);
    }
    unsigned short* d = xbf + ((size_t)b * 514 + tp) * 512 + c8 * 8;
    *(uint4*)d = *(const uint4*)v;
}

// w [dir][g][o][c][tap] fp32 -> wbf [dir*2048+m][tap*Cin+c] bf16
__global__ __launch_bounds__(256) void conv_w(const float* __restrict__ src,
                                              unsigned short* __restrict__ dst,
                                              int Cin, int total) {
    const int i = blockIdx.x * 256 + threadIdx.x;
    if (i >= total) return;
    const int K = 2 * Cin;
    const int dm = i / K;
    const int kp = i - dm * K;
    const int tap = (kp >= Cin) ? 1 : 0;
    const int c = kp - tap * Cin;
    dst[i] = f2bf(src[((size_t)dm * Cin + c) * 2 + tap]);
}

// zero the pad rows of h1bf [b][tp][1024], tp=0 and tp=513
__global__ __launch_bounds__(256) void zero_h1pad(unsigned short* __restrict__ h1bf) {
    const int i = blockIdx.x * 256 + threadIdx.x;  // 65536
    const int c = i & 1023;
    const int b = (i >> 10) & 31;
    const int tp = (i >> 15) ? 513 : 0;
    h1bf[((size_t)b * 514 + tp) * 1024 + c] = 0;
}

// ---------------- bf16 MFMA gate GEMM ----------------
// C[m=(g,o)][n=(b,t)] = sum_{k'=tap*Cin+c} Wbf[m][k'] * Xbf[b][tp(t,tap)][c]
// tp = dir==0 ? t+tap : 513-t-tap   (pad rows absorb the boundary)
// out: gates[g][n][o] fp32
__global__ __launch_bounds__(256) void gate_gemm_bf16(
    const unsigned short* __restrict__ Wbf,  // [2048][K]
    const unsigned short* __restrict__ Xbf,  // [32][514][Cin]
    float* __restrict__ gates,
    int Cin, int dir)
{
    const int K = 2 * Cin;
    __shared__ __align__(16) unsigned short As[128 * 64];  // 16KB, [m][64] swizzled
    __shared__ __align__(16) unsigned short Bs[128 * 64];  // 16KB, [n][64] swizzled

    const int tid = threadIdx.x;
    const int lane = tid & 63;
    const int wave = tid >> 6;
    const int m0 = blockIdx.x * 128;
    const int n0 = blockIdx.y * 128;
    const int wm = (wave & 1) * 64;
    const int wn = (wave >> 1) * 64;

    // loader precompute (4 chunks of A + 4 of B per k-step; chunk = 16B)
    size_t aoff[4];
    int tB[4], bB[4], kkB[4];
#pragma unroll
    for (int r = 0; r < 4; ++r) {
        const int q = r * 256 + tid;
        const int row = q >> 3;
        const int j = q & 7;
        const int kk = j ^ ((row >> 1) & 7);   // XOR swizzle baked into fetch addr
        aoff[r] = (size_t)(m0 + row) * K + kk * 8;
        const int n = n0 + row;
        tB[r] = n & 511;
        bB[r] = n >> 9;
        kkB[r] = kk;
    }

    f32x4 acc[4][4] = {};

    for (int k0 = 0; k0 < K; k0 += 64) {
        const int tap = (k0 >= Cin) ? 1 : 0;
        const int c0 = k0 - tap * Cin;
#pragma unroll
        for (int r = 0; r < 4; ++r)
            gload16(Wbf + aoff[r] + k0, As + (size_t)(r * 256 + tid) * 8);
#pragma unroll
        for (int r = 0; r < 4; ++r) {
            const int tp = dir ? (513 - tB[r] - tap) : (tB[r] + tap);
            const unsigned short* src =
                Xbf + ((size_t)bB[r] * 514 + tp) * Cin + c0 + kkB[r] * 8;
            gload16(src, Bs + (size_t)(r * 256 + tid) * 8);
        }
        __builtin_amdgcn_s_waitcnt(0);
        __syncthreads();

#pragma unroll
        for (int kh = 0; kh < 2; ++kh) {
            const int jr = (lane >> 4) + kh * 4;
            bf16x8 af[4], bfr[4];
#pragma unroll
            for (int f = 0; f < 4; ++f) {
                const int ma = wm + f * 16 + (lane & 15);
                const int ja = jr ^ ((ma >> 1) & 7);
                af[f] = *(const bf16x8*)&As[ma * 64 + ja * 8];
                const int nb = wn + f * 16 + (lane & 15);
                const int jb = jr ^ ((nb >> 1) & 7);
                bfr[f] = *(const bf16x8*)&Bs[nb * 64 + jb * 8];
            }
#pragma unroll
            for (int fm = 0; fm < 4; ++fm)
#pragma unroll
                for (int fn = 0; fn < 4; ++fn)
                    acc[fm][fn] = __builtin_amdgcn_mfma_f32_16x16x32_bf16(
                        af[fm], bfr[fn], acc[fm][fn], 0, 0, 0);
        }
        __syncthreads();
    }

    // epilogue: C layout col=lane&15 (n), row=(lane>>4)*4+reg (m)
    const int g = m0 >> 9;
    const int obase = (m0 & 511) + wm + ((lane >> 4) << 2);
    float* gb = gates + (size_t)g * PLANE;
#pragma unroll
    for (int fm = 0; fm < 4; ++fm)
#pragma unroll
        for (int fn = 0; fn < 4; ++fn) {
            const int o = obase + fm * 16;
            const int n = n0 + wn + fn * 16 + (lane & 15);
            *(f32x4*)&gb[(size_t)n * 512 + o] = acc[fm][fn];
        }
}

// ---------------- scan kernels (unchanged math) ----------------

__global__ __launch_bounds__(256) void scan_A(
    float* __restrict__ gates, const float* __restrict__ bias,
    float* __restrict__ Fsum, float* __restrict__ Ssum)
{
    const int idx = blockIdx.x * 256 + threadIdx.x;
    const int o = idx & 511;
    const int b = (idx >> 9) & 31;
    const int chunk = idx >> 14;
    const float bz = bias[o];
    const float bf = bias[512 + o];
    const float bi = bias[1536 + o];
    float F = 1.0f, S = 0.0f;
    const int tbase = chunk * 64;
    for (int tt = 0; tt < 64; ++tt) {
        const size_t idxg = ((size_t)(b * 512 + tbase + tt)) * 512 + o;
        const float zp = gates[idxg] + bz;
        const float fp = gates[PLANE + idxg] + bf;
        const float ip = gates[3 * PLANE + idxg] + bi;
        const float f = sigm(fp);
        const float iz = sigm(ip) * tanh_fast(zp);
        gates[PLANE + idxg] = f;
        gates[3 * PLANE + idxg] = iz;
        F *= f;
        S = f * S + iz;
    }
    Fsum[idx] = F;
    Ssum[idx] = S;
}

__global__ __launch_bounds__(256) void scan_B(
    const float* __restrict__ Fsum, const float* __restrict__ Ssum,
    float* __restrict__ cstart)
{
    const int i = blockIdx.x * 256 + threadIdx.x;
    float c = 0.0f;
    for (int ch = 0; ch < 8; ++ch) {
        cstart[ch * 16384 + i] = c;
        c = Fsum[ch * 16384 + i] * c + Ssum[ch * 16384 + i];
    }
}

// isLayer2: write fp32 to out (T,B,2H); else bf16 to h1bf [b][t+1][2H]
__global__ __launch_bounds__(256) void scan_C(
    const float* __restrict__ gates, const float* __restrict__ bias,
    const float* __restrict__ cstart, float* __restrict__ out,
    unsigned short* __restrict__ h1bf,
    float* __restrict__ hn, int isLayer2, int dirH)
{
    const int idx = blockIdx.x * 256 + threadIdx.x;
    const int o = idx & 511;
    const int b = (idx >> 9) & 31;
    const int chunk = idx >> 14;
    const float bo_ = bias[1024 + o];
    float c = cstart[idx];
    const int tbase = chunk * 64;
    for (int tt = 0; tt < 64; ++tt) {
        const int t = tbase + tt;
        const size_t idxg = ((size_t)(b * 512 + t)) * 512 + o;
        const float f = gates[PLANE + idxg];
        const float iz = gates[3 * PLANE + idxg];
        const float op = gates[2 * PLANE + idxg] + bo_;
        c = f * c + iz;
        const float outv = sigm(op) * c;
        if (isLayer2) {
            out[((size_t)t * Bn + b) * 1024 + dirH + o] = outv;
        } else {
            h1bf[((size_t)b * 514 + (t + 1)) * 1024 + dirH + o] = f2bf(outv);
        }
        const bool isLast = (dirH == 0) ? (t == Tn - 2) : (t == 0);
        if (isLast) hn[(size_t)b * 1024 + dirH + o] = outv;
    }
}

extern "C" void kernel_launch(void* const* d_in, const int* in_sizes, int n_in,
                              void* d_out, int out_size, void* d_ws, size_t ws_size,
                              hipStream_t stream) {
    const float* x  = (const float*)d_in[0];
    const float* w0 = (const float*)d_in[1];
    const float* b0 = (const float*)d_in[2];
    const float* w1 = (const float*)d_in[3];
    const float* b1 = (const float*)d_in[4];
    float* out = (float*)d_out;
    float* ws = (float*)d_ws;

    float* gates = ws;                              // 33,554,432 f
    float* Fsum  = gates + 4 * PLANE;               // 131072
    float* Ssum  = Fsum + 131072;
    float* cst   = Ssum + 131072;
    unsigned short* xbf  = (unsigned short*)(cst + 131072);  // 32*514*512
    unsigned short* h1bf = xbf + (size_t)32 * 514 * 512;     // 32*514*1024
    unsigned short* w0bf = h1bf + (size_t)32 * 514 * 1024;   // 2*2048*1024
    unsigned short* w1bf = w0bf + (size_t)2 * 2048 * 1024;   // 2*2048*2048
    float* hn = out + 16777216;

    // conversions (every launch; ws is re-poisoned by harness)
    conv_x<<<4112, 256, 0, stream>>>(x, xbf);
    conv_w<<<16384, 256, 0, stream>>>(w0, w0bf, 512, 4194304);
    conv_w<<<32768, 256, 0, stream>>>(w1, w1bf, 1024, 8388608);
    zero_h1pad<<<256, 256, 0, stream>>>(h1bf);

    const dim3 gg(16, 128);  // x = m-tiles (fastest) for B-tile L2 reuse

    // ---- Layer 1, forward ----
    gate_gemm_bf16<<<gg, 256, 0, stream>>>(w0bf, xbf, gates, 512, 0);
    scan_A<<<512, 256, 0, stream>>>(gates, b0, Fsum, Ssum);
    scan_B<<<64, 256, 0, stream>>>(Fsum, Ssum, cst);
    scan_C<<<512, 256, 0, stream>>>(gates, b0, cst, out, h1bf, hn, 0, 0);
    // ---- Layer 1, reverse ----
    gate_gemm_bf16<<<gg, 256, 0, stream>>>(w0bf + (size_t)2048 * 1024, xbf, gates, 512, 1);
    scan_A<<<512, 256, 0, stream>>>(gates, b0 + 2048, Fsum, Ssum);
    scan_B<<<64, 256, 0, stream>>>(Fsum, Ssum, cst);
    scan_C<<<512, 256, 0, stream>>>(gates, b0 + 2048, cst, out, h1bf, hn, 0, 512);
    // ---- Layer 2, forward ----
    gate_gemm_bf16<<<gg, 256, 0, stream>>>(w1bf, h1bf, gates, 1024, 0);
    scan_A<<<512, 256, 0, stream>>>(gates, b1, Fsum, Ssum);
    scan_B<<<64, 256, 0, stream>>>(Fsum, Ssum, cst);
    scan_C<<<512, 256, 0, stream>>>(gates, b1, cst, out, h1bf, hn + 32768, 1, 0);
    // ---- Layer 2, reverse ----
    gate_gemm_bf16<<<gg, 256, 0, stream>>>(w1bf + (size_t)2048 * 2048, h1bf, gates, 1024, 1);
    scan_A<<<512, 256, 0, stream>>>(gates, b1 + 2048, Fsum, Ssum);
    scan_B<<<64, 256, 0, stream>>>(Fsum, Ssum, cst);
    scan_C<<<512, 256, 0, stream>>>(gates, b1 + 2048, cst, out, h1bf, hn + 32768, 1, 512);
}

// Round 3
// 813.874 us; speedup vs baseline: 6.4854x; 1.1917x over previous
//
#include <hip/hip_runtime.h>
#include <cstddef>
#include <cstdint>

#define Tn 512
#define Bn 32
#define Hn 512
static const size_t PLANE = 8388608; // Bn*Tn*Hn

typedef float f32x4 __attribute__((ext_vector_type(4)));
typedef __bf16 bf16x8 __attribute__((ext_vector_type(8)));
typedef _Float16 h2 __attribute__((ext_vector_type(2)));

__device__ __forceinline__ float sigm(float x) { return 1.0f / (1.0f + __expf(-x)); }
__device__ __forceinline__ float tanh_fast(float x) { return 2.0f / (1.0f + __expf(-2.0f * x)) - 1.0f; }
__device__ __forceinline__ unsigned short f2bf(float f) {
    unsigned int u = __float_as_uint(f);
    u += 0x7FFF + ((u >> 16) & 1);   // RNE
    return (unsigned short)(u >> 16);
}
__device__ __forceinline__ void gload16(const void* g, void* l) {
    __builtin_amdgcn_global_load_lds(
        (const __attribute__((address_space(1))) unsigned int*)g,
        (__attribute__((address_space(3))) unsigned int*)l, 16, 0, 0);
}

// ---------------- conversion kernels ----------------

// x (T,B,C) fp32 -> xbf [b][t+1][c] bf16 with zero rows at tp=0 and tp=513
__global__ __launch_bounds__(256) void conv_x(const float* __restrict__ x,
                                              unsigned short* __restrict__ xbf) {
    const int i = blockIdx.x * 256 + threadIdx.x;  // 32*514*64
    const int c8 = i & 63;
    const int tp = (i >> 6) % 514;
    const int b  = (i >> 6) / 514;
    unsigned short v[8];
    if (tp == 0 || tp == 513) {
#pragma unroll
        for (int j = 0; j < 8; ++j) v[j] = 0;
    } else {
        const float* s = x + ((size_t)(tp - 1) * Bn + b) * 512 + c8 * 8;
#pragma unroll
        for (int j = 0; j < 8; ++j) v[j] = f2bf(s[j]);
    }
    unsigned short* d = xbf + ((size_t)b * 514 + tp) * 512 + c8 * 8;
    *(uint4*)d = *(const uint4*)v;
}

// w [dir][g][o][c][tap] fp32 -> wbf [dir][m'=o*4+g][k'=tap*Cin+c] bf16
__global__ __launch_bounds__(256) void conv_w(const float* __restrict__ src,
                                              unsigned short* __restrict__ dst,
                                              int Cin, int total) {
    const int i = blockIdx.x * 256 + threadIdx.x;
    if (i >= total) return;
    const int K = 2 * Cin;
    const int dm2 = i / K;            // dir*2048 + m'
    const int kp = i - dm2 * K;
    const int dir = dm2 >> 11;
    const int mp = dm2 & 2047;
    const int o = mp >> 2;
    const int g = mp & 3;
    const int tap = (kp >= Cin) ? 1 : 0;
    const int c = kp - tap * Cin;
    dst[i] = f2bf(src[((((size_t)dir * 4 + g) * 512 + o) * Cin + c) * 2 + tap]);
}

// zero the pad rows of h1bf [b][tp][1024], tp=0 and tp=513
__global__ __launch_bounds__(256) void zero_h1pad(unsigned short* __restrict__ h1bf) {
    const int i = blockIdx.x * 256 + threadIdx.x;  // 65536
    const int c = i & 1023;
    const int b = (i >> 10) & 31;
    const int tp = (i >> 15) ? 513 : 0;
    h1bf[((size_t)b * 514 + tp) * 1024 + c] = 0;
}

// ---------------- bf16 MFMA gate GEMM + fused activation epilogue ----------------
// C[m'=o*4+g][n=(b,t)] ; each C fragment (f32x4) = {z,f,o,i} of one (o,n).
// Epilogue: f=sigm(f+bf), iz=sigm(i+bi)*tanh(z+bz), os=sigm(o+bo);
// write fiz (h2, [n][512]) and os (half, [n][512]) via LDS transpose, coalesced.
__global__ __launch_bounds__(256) void gate_gemm_bf16(
    const unsigned short* __restrict__ Wbf,  // [2048][K], rows m'=o*4+g
    const unsigned short* __restrict__ Xbf,  // [32][514][Cin]
    const float* __restrict__ bias,          // [4][512] (dir-offset applied)
    h2* __restrict__ fiz,                    // [16384][512]
    _Float16* __restrict__ osb,              // [16384][512]
    int Cin, int dir)
{
    const int K = 2 * Cin;
    __shared__ __align__(16) unsigned char smem[32768];
    unsigned short* As = (unsigned short*)smem;            // [128][64] swizzled
    unsigned short* Bs = (unsigned short*)(smem + 16384);  // [128][64] swizzled

    const int tid = threadIdx.x;
    const int lane = tid & 63;
    const int wave = tid >> 6;
    const int n0 = blockIdx.x * 128;   // n fast => XCD = n-tile % 8 (B-slice locality)
    const int m0 = blockIdx.y * 128;
    const int wm = (wave & 1) * 64;
    const int wn = (wave >> 1) * 64;

    size_t aoff[4];
    int tB[4], bB[4], kkB[4];
#pragma unroll
    for (int r = 0; r < 4; ++r) {
        const int q = r * 256 + tid;
        const int row = q >> 3;
        const int j = q & 7;
        const int kk = j ^ ((row >> 1) & 7);   // XOR swizzle baked into fetch addr
        aoff[r] = (size_t)(m0 + row) * K + kk * 8;
        const int n = n0 + row;
        tB[r] = n & 511;
        bB[r] = n >> 9;
        kkB[r] = kk;
    }

    f32x4 acc[4][4] = {};

    for (int k0 = 0; k0 < K; k0 += 64) {
        const int tap = (k0 >= Cin) ? 1 : 0;
        const int c0 = k0 - tap * Cin;
#pragma unroll
        for (int r = 0; r < 4; ++r)
            gload16(Wbf + aoff[r] + k0, As + (size_t)(r * 256 + tid) * 8);
#pragma unroll
        for (int r = 0; r < 4; ++r) {
            const int tp = dir ? (513 - tB[r] - tap) : (tB[r] + tap);
            const unsigned short* src =
                Xbf + ((size_t)bB[r] * 514 + tp) * Cin + c0 + kkB[r] * 8;
            gload16(src, Bs + (size_t)(r * 256 + tid) * 8);
        }
        __builtin_amdgcn_s_waitcnt(0);
        __syncthreads();

#pragma unroll
        for (int kh = 0; kh < 2; ++kh) {
            const int jr = (lane >> 4) + kh * 4;
            bf16x8 af[4], bfr[4];
#pragma unroll
            for (int f = 0; f < 4; ++f) {
                const int ma = wm + f * 16 + (lane & 15);
                const int ja = jr ^ ((ma >> 1) & 7);
                af[f] = *(const bf16x8*)&As[ma * 64 + ja * 8];
                const int nb = wn + f * 16 + (lane & 15);
                const int jb = jr ^ ((nb >> 1) & 7);
                bfr[f] = *(const bf16x8*)&Bs[nb * 64 + jb * 8];
            }
#pragma unroll
            for (int fm = 0; fm < 4; ++fm)
#pragma unroll
                for (int fn = 0; fn < 4; ++fn)
                    acc[fm][fn] = __builtin_amdgcn_mfma_f32_16x16x32_bf16(
                        af[fm], bfr[fn], acc[fm][fn], 0, 0, 0);
        }
        __syncthreads();
    }

    // ---- fused activation epilogue ----
    const int q = lane >> 4;
    const int o0 = blockIdx.y * 32;
    float Bz[4], Bf[4], Bo[4], Bi[4];
#pragma unroll
    for (int fm = 0; fm < 4; ++fm) {
        const int o = o0 + (wm >> 2) + fm * 4 + q;
        Bz[fm] = bias[o];
        Bf[fm] = bias[512 + o];
        Bo[fm] = bias[1024 + o];
        Bi[fm] = bias[1536 + o];
    }
    // LDS transpose buffers (alias As/Bs; safe: K-loop ended with __syncthreads)
    h2* Lfiz = (h2*)smem;                          // [128][36] rows 144B (16B-aligned)
    _Float16* Los = (_Float16*)(smem + 18432);     // [128][40] rows 80B (16B-aligned)
#pragma unroll
    for (int fm = 0; fm < 4; ++fm) {
        const int ol = (wm >> 2) + fm * 4 + q;
#pragma unroll
        for (int fn = 0; fn < 4; ++fn) {
            f32x4 v = acc[fm][fn];
            const float f  = sigm(v.y + Bf[fm]);
            const float iz = sigm(v.w + Bi[fm]) * tanh_fast(v.x + Bz[fm]);
            const float os = sigm(v.z + Bo[fm]);
            const int nl = wn + fn * 16 + (lane & 15);
            h2 p; p.x = (_Float16)f; p.y = (_Float16)iz;
            Lfiz[nl * 36 + ol] = p;
            Los[nl * 40 + ol] = (_Float16)os;
        }
    }
    __syncthreads();
    // coalesced write-out: fiz 128 rows x 128B, os 128 rows x 64B
#pragma unroll
    for (int l = 0; l < 4; ++l) {
        const int idx = l * 256 + tid;
        const int row = idx >> 3;
        const int col = idx & 7;
        uint4 v = *(const uint4*)((const unsigned char*)smem + row * 144 + col * 16);
        ((uint4*)(fiz + (size_t)(n0 + row) * 512 + o0))[col] = v;
    }
#pragma unroll
    for (int l = 0; l < 2; ++l) {
        const int idx = l * 256 + tid;
        const int row = idx >> 2;
        const int col = idx & 3;
        uint4 v = *(const uint4*)((const unsigned char*)smem + 18432 + row * 80 + col * 16);
        ((uint4*)(osb + (size_t)(n0 + row) * 512 + o0))[col] = v;
    }
}

// ---------------- scan kernels ----------------

__global__ __launch_bounds__(256) void scan_A(
    const h2* __restrict__ fiz,
    float* __restrict__ Fsum, float* __restrict__ Ssum)
{
    const int idx = blockIdx.x * 256 + threadIdx.x;  // 8 chunks * 32 b * 512 o
    const int o = idx & 511;
    const int b = (idx >> 9) & 31;
    const int chunk = idx >> 14;
    float F = 1.0f, S = 0.0f;
    const int tbase = chunk * 64;
    for (int tt = 0; tt < 64; ++tt) {
        const h2 v = fiz[((size_t)(b * 512 + tbase + tt)) * 512 + o];
        const float f = (float)v.x;
        const float iz = (float)v.y;
        F *= f;
        S = f * S + iz;
    }
    Fsum[idx] = F;
    Ssum[idx] = S;
}

__global__ __launch_bounds__(256) void scan_B(
    const float* __restrict__ Fsum, const float* __restrict__ Ssum,
    float* __restrict__ cstart)
{
    const int i = blockIdx.x * 256 + threadIdx.x;
    float c = 0.0f;
    for (int ch = 0; ch < 8; ++ch) {
        cstart[ch * 16384 + i] = c;
        c = Fsum[ch * 16384 + i] * c + Ssum[ch * 16384 + i];
    }
}

// isLayer2: write fp32 to out (T,B,2H); else bf16 to h1bf [b][t+1][2H]
__global__ __launch_bounds__(256) void scan_C(
    const h2* __restrict__ fiz, const _Float16* __restrict__ osb,
    const float* __restrict__ cstart, float* __restrict__ out,
    unsigned short* __restrict__ h1bf,
    float* __restrict__ hn, int isLayer2, int dirH)
{
    const int idx = blockIdx.x * 256 + threadIdx.x;
    const int o = idx & 511;
    const int b = (idx >> 9) & 31;
    const int chunk = idx >> 14;
    float c = cstart[idx];
    const int tbase = chunk * 64;
    for (int tt = 0; tt < 64; ++tt) {
        const int t = tbase + tt;
        const size_t idxg = ((size_t)(b * 512 + t)) * 512 + o;
        const h2 v = fiz[idxg];
        const float f = (float)v.x;
        const float iz = (float)v.y;
        const float os = (float)osb[idxg];
        c = f * c + iz;
        const float outv = os * c;
        if (isLayer2) {
            out[((size_t)t * Bn + b) * 1024 + dirH + o] = outv;
        } else {
            h1bf[((size_t)b * 514 + (t + 1)) * 1024 + dirH + o] = f2bf(outv);
        }
        const bool isLast = (dirH == 0) ? (t == Tn - 2) : (t == 0);
        if (isLast) hn[(size_t)b * 1024 + dirH + o] = outv;
    }
}

extern "C" void kernel_launch(void* const* d_in, const int* in_sizes, int n_in,
                              void* d_out, int out_size, void* d_ws, size_t ws_size,
                              hipStream_t stream) {
    const float* x  = (const float*)d_in[0];
    const float* w0 = (const float*)d_in[1];
    const float* b0 = (const float*)d_in[2];
    const float* w1 = (const float*)d_in[3];
    const float* b1 = (const float*)d_in[4];
    float* out = (float*)d_out;
    float* ws = (float*)d_ws;

    h2* fiz        = (h2*)ws;                               // 8388608 * 4B
    _Float16* osb  = (_Float16*)(ws + PLANE);               // 8388608 * 2B
    float* Fsum    = ws + PLANE + PLANE / 2;                // 131072
    float* Ssum    = Fsum + 131072;
    float* cst     = Ssum + 131072;
    unsigned short* xbf  = (unsigned short*)(cst + 131072); // 32*514*512
    unsigned short* h1bf = xbf + (size_t)32 * 514 * 512;    // 32*514*1024
    unsigned short* w0bf = h1bf + (size_t)32 * 514 * 1024;  // 2*2048*1024
    unsigned short* w1bf = w0bf + (size_t)2 * 2048 * 1024;  // 2*2048*2048
    float* hn = out + 16777216;

    conv_x<<<4112, 256, 0, stream>>>(x, xbf);
    conv_w<<<16384, 256, 0, stream>>>(w0, w0bf, 512, 4194304);
    conv_w<<<32768, 256, 0, stream>>>(w1, w1bf, 1024, 8388608);
    zero_h1pad<<<256, 256, 0, stream>>>(h1bf);

    const dim3 gg(128, 16);  // x = n-tiles (fastest): XCD owns an n-stripe, A streams

    // ---- Layer 1, forward ----
    gate_gemm_bf16<<<gg, 256, 0, stream>>>(w0bf, xbf, b0, fiz, osb, 512, 0);
    scan_A<<<512, 256, 0, stream>>>(fiz, Fsum, Ssum);
    scan_B<<<64, 256, 0, stream>>>(Fsum, Ssum, cst);
    scan_C<<<512, 256, 0, stream>>>(fiz, osb, cst, out, h1bf, hn, 0, 0);
    // ---- Layer 1, reverse ----
    gate_gemm_bf16<<<gg, 256, 0, stream>>>(w0bf + (size_t)2048 * 1024, xbf, b0 + 2048, fiz, osb, 512, 1);
    scan_A<<<512, 256, 0, stream>>>(fiz, Fsum, Ssum);
    scan_B<<<64, 256, 0, stream>>>(Fsum, Ssum, cst);
    scan_C<<<512, 256, 0, stream>>>(fiz, osb, cst, out, h1bf, hn, 0, 512);
    // ---- Layer 2, forward ----
    gate_gemm_bf16<<<gg, 256, 0, stream>>>(w1bf, h1bf, b1, fiz, osb, 1024, 0);
    scan_A<<<512, 256, 0, stream>>>(fiz, Fsum, Ssum);
    scan_B<<<64, 256, 0, stream>>>(Fsum, Ssum, cst);
    scan_C<<<512, 256, 0, stream>>>(fiz, osb, cst, out, h1bf, hn + 32768, 1, 0);
    // ---- Layer 2, reverse ----
    gate_gemm_bf16<<<gg, 256, 0, stream>>>(w1bf + (size_t)2048 * 2048, h1bf, b1 + 2048, fiz, osb, 1024, 1);
    scan_A<<<512, 256, 0, stream>>>(fiz, Fsum, Ssum);
    scan_B<<<64, 256, 0, stream>>>(Fsum, Ssum, cst);
    scan_C<<<512, 256, 0, stream>>>(fiz, osb, cst, out, h1bf, hn + 32768, 1, 512);
}

// Round 6
// 696.402 us; speedup vs baseline: 7.5794x; 1.1687x over previous
//
#include <hip/hip_runtime.h>
#include <cstddef>
#include <cstdint>

#define Tn 512
#define Bn 32
#define Hn 512
static const size_t PLANE = 8388608; // Bn*Tn*Hn

typedef float f32x4 __attribute__((ext_vector_type(4)));
typedef __bf16 bf16x8 __attribute__((ext_vector_type(8)));
typedef _Float16 h2 __attribute__((ext_vector_type(2)));

__device__ __forceinline__ float sigm(float x) { return 1.0f / (1.0f + __expf(-x)); }
__device__ __forceinline__ float tanh_fast(float x) { return 2.0f / (1.0f + __expf(-2.0f * x)) - 1.0f; }
__device__ __forceinline__ unsigned short f2bf(float f) {
    unsigned int u = __float_as_uint(f);
    u += 0x7FFF + ((u >> 16) & 1);   // RNE
    return (unsigned short)(u >> 16);
}

// ---------------- conversion kernels ----------------

__global__ __launch_bounds__(256) void conv_x(const float* __restrict__ x,
                                              unsigned short* __restrict__ xbf) {
    const int i = blockIdx.x * 256 + threadIdx.x;  // 32*514*64
    const int c8 = i & 63;
    const int tp = (i >> 6) % 514;
    const int b  = (i >> 6) / 514;
    unsigned short v[8];
    if (tp == 0 || tp == 513) {
#pragma unroll
        for (int j = 0; j < 8; ++j) v[j] = 0;
    } else {
        const float* s = x + ((size_t)(tp - 1) * Bn + b) * 512 + c8 * 8;
#pragma unroll
        for (int j = 0; j < 8; ++j) v[j] = f2bf(s[j]);
    }
    unsigned short* d = xbf + ((size_t)b * 514 + tp) * 512 + c8 * 8;
    *(uint4*)d = *(const uint4*)v;
}

// w [dir][g][o][c][tap] fp32 -> wbf [dir][m'=o*4+g][k'=tap*Cin+c] bf16
__global__ __launch_bounds__(256) void conv_w(const float* __restrict__ src,
                                              unsigned short* __restrict__ dst,
                                              int Cin, int total) {
    const int i = blockIdx.x * 256 + threadIdx.x;
    if (i >= total) return;
    const int K = 2 * Cin;
    const int dm2 = i / K;            // dir*2048 + m'
    const int kp = i - dm2 * K;
    const int dir = dm2 >> 11;
    const int mp = dm2 & 2047;
    const int o = mp >> 2;
    const int g = mp & 3;
    const int tap = (kp >= Cin) ? 1 : 0;
    const int c = kp - tap * Cin;
    dst[i] = f2bf(src[((((size_t)dir * 4 + g) * 512 + o) * Cin + c) * 2 + tap]);
}

__global__ __launch_bounds__(256) void zero_h1pad(unsigned short* __restrict__ h1bf) {
    const int i = blockIdx.x * 256 + threadIdx.x;  // 65536
    const int c = i & 1023;
    const int b = (i >> 10) & 31;
    const int tp = (i >> 15) ? 513 : 0;
    h1bf[((size_t)b * 514 + tp) * 1024 + c] = 0;
}

// ---------------- bf16 MFMA gate GEMM + fused activation epilogue ----------------
// C[m'=o*4+g][n=(b,t)] ; each C fragment (f32x4) = {z,f,o,i} of one (o,n).
// Templated on CIN so the K-loop fully unrolls; addressing hoisted; offset=0 always.
template <int CIN>
__global__ __launch_bounds__(256) void gate_gemm_bf16(
    const unsigned short* __restrict__ Wbf,  // [2048][2*CIN], rows m'=o*4+g
    const unsigned short* __restrict__ Xbf,  // [32][514][CIN]
    const float* __restrict__ bias,          // [4][512] (dir-offset applied)
    h2* __restrict__ fiz,                    // [16384][512]
    _Float16* __restrict__ osb,              // [16384][512]
    int dir)
{
    __shared__ __align__(16) unsigned char smem[32768];
    unsigned short* As = (unsigned short*)smem;            // [128][64] swizzled
    unsigned short* Bs = (unsigned short*)(smem + 16384);  // [128][64] swizzled

    const int tid = threadIdx.x;
    const int lane = tid & 63;
    const int wave = tid >> 6;
    const int n0 = blockIdx.x * 128;   // n fast => XCD owns an n-stripe
    const int m0 = blockIdx.y * 128;
    const int wm = (wave & 1) * 64;
    const int wn = (wave >> 1) * 64;

    // ---- hoisted loader state ----
    const unsigned short* pA[4];   // per loader-row A pointer (tap 0 base)
    const unsigned short* pB0[4];  // per loader-row B pointer, tap=0
    unsigned short* ldst[8];       // fixed LDS destinations
#pragma unroll
    for (int r = 0; r < 4; ++r) {
        const int q = r * 256 + tid;
        const int row = q >> 3;
        const int j = q & 7;
        const int kk = j ^ ((row >> 1) & 7);   // XOR swizzle baked into fetch addr
        pA[r] = Wbf + (size_t)(m0 + row) * (2 * CIN) + kk * 8;
        const int n = n0 + row;
        const int t = n & 511;
        const int b = n >> 9;
        const int tp0 = dir ? (513 - t) : t;
        pB0[r] = Xbf + ((size_t)b * 514 + tp0) * CIN + kk * 8;
        ldst[r] = As + (size_t)q * 8;
        ldst[r + 4] = Bs + (size_t)q * 8;
    }
    const int dstep = dir ? -CIN : CIN;  // tap=1 B shift (elements)

    // ---- hoisted LDS fragment offsets (elements) ----
    int offA[2][4], offB[2][4];
#pragma unroll
    for (int kh = 0; kh < 2; ++kh) {
        const int jr = (lane >> 4) + kh * 4;
#pragma unroll
        for (int f = 0; f < 4; ++f) {
            const int ma = wm + f * 16 + (lane & 15);
            offA[kh][f] = ma * 64 + (jr ^ ((ma >> 1) & 7)) * 8;
            const int nb = wn + f * 16 + (lane & 15);
            offB[kh][f] = nb * 64 + (jr ^ ((nb >> 1) & 7)) * 8;
        }
    }

    f32x4 acc[4][4] = {};

    auto mfma_stage = [&]() {
#pragma unroll
        for (int kh = 0; kh < 2; ++kh) {
            bf16x8 af[4], bfr[4];
#pragma unroll
            for (int f = 0; f < 4; ++f) {
                af[f] = *(const bf16x8*)&As[offA[kh][f]];
                bfr[f] = *(const bf16x8*)&Bs[offB[kh][f]];
            }
#pragma unroll
            for (int fm = 0; fm < 4; ++fm)
#pragma unroll
                for (int fn = 0; fn < 4; ++fn)
                    acc[fm][fn] = __builtin_amdgcn_mfma_f32_16x16x32_bf16(
                        af[fm], bfr[fn], acc[fm][fn], 0, 0, 0);
        }
    };

#define GL(P, D) __builtin_amdgcn_global_load_lds( \
        (const __attribute__((address_space(1))) unsigned int*)(P), \
        (__attribute__((address_space(3))) unsigned int*)(D), 16, 0, 0)

#pragma unroll
    for (int tap = 0; tap < 2; ++tap) {
        const unsigned short* a0 = pA[0] + tap * CIN;
        const unsigned short* a1 = pA[1] + tap * CIN;
        const unsigned short* a2 = pA[2] + tap * CIN;
        const unsigned short* a3 = pA[3] + tap * CIN;
        const unsigned short* b0 = pB0[0] + tap * dstep;
        const unsigned short* b1 = pB0[1] + tap * dstep;
        const unsigned short* b2 = pB0[2] + tap * dstep;
        const unsigned short* b3 = pB0[3] + tap * dstep;
#pragma unroll
        for (int s = 0; s < CIN / 64; ++s) {   // BK=64 steps
            GL(a0, ldst[0]); GL(a1, ldst[1]);
            GL(a2, ldst[2]); GL(a3, ldst[3]);
            GL(b0, ldst[4]); GL(b1, ldst[5]);
            GL(b2, ldst[6]); GL(b3, ldst[7]);
            __builtin_amdgcn_s_waitcnt(0);
            __syncthreads();
            mfma_stage();
            __syncthreads();
            a0 += 64; a1 += 64; a2 += 64; a3 += 64;
            b0 += 64; b1 += 64; b2 += 64; b3 += 64;
        }
    }
#undef GL

    // ---- fused activation epilogue ----
    const int q = lane >> 4;
    const int o0 = blockIdx.y * 32;
    float Bz[4], Bf[4], Bo[4], Bi[4];
#pragma unroll
    for (int fm = 0; fm < 4; ++fm) {
        const int o = o0 + (wm >> 2) + fm * 4 + q;
        Bz[fm] = bias[o];
        Bf[fm] = bias[512 + o];
        Bo[fm] = bias[1024 + o];
        Bi[fm] = bias[1536 + o];
    }
    h2* Lfiz = (h2*)smem;                          // [128][36] rows 144B
    _Float16* Los = (_Float16*)(smem + 18432);     // [128][40] rows 80B
#pragma unroll
    for (int fm = 0; fm < 4; ++fm) {
        const int ol = (wm >> 2) + fm * 4 + q;
#pragma unroll
        for (int fn = 0; fn < 4; ++fn) {
            f32x4 v = acc[fm][fn];
            const float f  = sigm(v.y + Bf[fm]);
            const float iz = sigm(v.w + Bi[fm]) * tanh_fast(v.x + Bz[fm]);
            const float os = sigm(v.z + Bo[fm]);
            const int nl = wn + fn * 16 + (lane & 15);
            h2 p; p.x = (_Float16)f; p.y = (_Float16)iz;
            Lfiz[nl * 36 + ol] = p;
            Los[nl * 40 + ol] = (_Float16)os;
        }
    }
    __syncthreads();
#pragma unroll
    for (int l = 0; l < 4; ++l) {
        const int idx = l * 256 + tid;
        const int row = idx >> 3;
        const int col = idx & 7;
        uint4 v = *(const uint4*)((const unsigned char*)smem + row * 144 + col * 16);
        ((uint4*)(fiz + (size_t)(n0 + row) * 512 + o0))[col] = v;
    }
#pragma unroll
    for (int l = 0; l < 2; ++l) {
        const int idx = l * 256 + tid;
        const int row = idx >> 2;
        const int col = idx & 3;
        uint4 v = *(const uint4*)((const unsigned char*)smem + 18432 + row * 80 + col * 16);
        ((uint4*)(osb + (size_t)(n0 + row) * 512 + o0))[col] = v;
    }
}

// ---------------- scan kernels ----------------

__global__ __launch_bounds__(256) void scan_A(
    const h2* __restrict__ fiz,
    float* __restrict__ Fsum, float* __restrict__ Ssum)
{
    const int idx = blockIdx.x * 256 + threadIdx.x;
    const int o = idx & 511;
    const int b = (idx >> 9) & 31;
    const int chunk = idx >> 14;
    float F = 1.0f, S = 0.0f;
    const int tbase = chunk * 64;
    for (int tt = 0; tt < 64; ++tt) {
        const h2 v = fiz[((size_t)(b * 512 + tbase + tt)) * 512 + o];
        const float f = (float)v.x;
        const float iz = (float)v.y;
        F *= f;
        S = f * S + iz;
    }
    Fsum[idx] = F;
    Ssum[idx] = S;
}

__global__ __launch_bounds__(256) void scan_B(
    const float* __restrict__ Fsum, const float* __restrict__ Ssum,
    float* __restrict__ cstart)
{
    const int i = blockIdx.x * 256 + threadIdx.x;
    float c = 0.0f;
    for (int ch = 0; ch < 8; ++ch) {
        cstart[ch * 16384 + i] = c;
        c = Fsum[ch * 16384 + i] * c + Ssum[ch * 16384 + i];
    }
}

__global__ __launch_bounds__(256) void scan_C(
    const h2* __restrict__ fiz, const _Float16* __restrict__ osb,
    const float* __restrict__ cstart, float* __restrict__ out,
    unsigned short* __restrict__ h1bf,
    float* __restrict__ hn, int isLayer2, int dirH)
{
    const int idx = blockIdx.x * 256 + threadIdx.x;
    const int o = idx & 511;
    const int b = (idx >> 9) & 31;
    const int chunk = idx >> 14;
    float c = cstart[idx];
    const int tbase = chunk * 64;
    for (int tt = 0; tt < 64; ++tt) {
        const int t = tbase + tt;
        const size_t idxg = ((size_t)(b * 512 + t)) * 512 + o;
        const h2 v = fiz[idxg];
        const float f = (float)v.x;
        const float iz = (float)v.y;
        const float os = (float)osb[idxg];
        c = f * c + iz;
        const float outv = os * c;
        if (isLayer2) {
            out[((size_t)t * Bn + b) * 1024 + dirH + o] = outv;
        } else {
            h1bf[((size_t)b * 514 + (t + 1)) * 1024 + dirH + o] = f2bf(outv);
        }
        const bool isLast = (dirH == 0) ? (t == Tn - 2) : (t == 0);
        if (isLast) hn[(size_t)b * 1024 + dirH + o] = outv;
    }
}

extern "C" void kernel_launch(void* const* d_in, const int* in_sizes, int n_in,
                              void* d_out, int out_size, void* d_ws, size_t ws_size,
                              hipStream_t stream) {
    const float* x  = (const float*)d_in[0];
    const float* w0 = (const float*)d_in[1];
    const float* b0 = (const float*)d_in[2];
    const float* w1 = (const float*)d_in[3];
    const float* b1 = (const float*)d_in[4];
    float* out = (float*)d_out;
    float* ws = (float*)d_ws;

    h2* fiz        = (h2*)ws;                               // 8388608 * 4B
    _Float16* osb  = (_Float16*)(ws + PLANE);               // 8388608 * 2B
    float* Fsum    = ws + PLANE + PLANE / 2;                // 131072
    float* Ssum    = Fsum + 131072;
    float* cst     = Ssum + 131072;
    unsigned short* xbf  = (unsigned short*)(cst + 131072); // 32*514*512
    unsigned short* h1bf = xbf + (size_t)32 * 514 * 512;    // 32*514*1024
    unsigned short* w0bf = h1bf + (size_t)32 * 514 * 1024;  // 2*2048*1024
    unsigned short* w1bf = w0bf + (size_t)2 * 2048 * 1024;  // 2*2048*2048
    float* hn = out + 16777216;

    conv_x<<<4112, 256, 0, stream>>>(x, xbf);
    conv_w<<<16384, 256, 0, stream>>>(w0, w0bf, 512, 4194304);
    conv_w<<<32768, 256, 0, stream>>>(w1, w1bf, 1024, 8388608);
    zero_h1pad<<<256, 256, 0, stream>>>(h1bf);

    const dim3 gg(128, 16);  // x = n-tiles (fastest)

    // ---- Layer 1, forward ----
    gate_gemm_bf16<512><<<gg, 256, 0, stream>>>(w0bf, xbf, b0, fiz, osb, 0);
    scan_A<<<512, 256, 0, stream>>>(fiz, Fsum, Ssum);
    scan_B<<<64, 256, 0, stream>>>(Fsum, Ssum, cst);
    scan_C<<<512, 256, 0, stream>>>(fiz, osb, cst, out, h1bf, hn, 0, 0);
    // ---- Layer 1, reverse ----
    gate_gemm_bf16<512><<<gg, 256, 0, stream>>>(w0bf + (size_t)2048 * 1024, xbf, b0 + 2048, fiz, osb, 1);
    scan_A<<<512, 256, 0, stream>>>(fiz, Fsum, Ssum);
    scan_B<<<64, 256, 0, stream>>>(Fsum, Ssum, cst);
    scan_C<<<512, 256, 0, stream>>>(fiz, osb, cst, out, h1bf, hn, 0, 512);
    // ---- Layer 2, forward ----
    gate_gemm_bf16<1024><<<gg, 256, 0, stream>>>(w1bf, h1bf, b1, fiz, osb, 0);
    scan_A<<<512, 256, 0, stream>>>(fiz, Fsum, Ssum);
    scan_B<<<64, 256, 0, stream>>>(Fsum, Ssum, cst);
    scan_C<<<512, 256, 0, stream>>>(fiz, osb, cst, out, h1bf, hn + 32768, 1, 0);
    // ---- Layer 2, reverse ----
    gate_gemm_bf16<1024><<<gg, 256, 0, stream>>>(w1bf + (size_t)2048 * 2048, h1bf, b1 + 2048, fiz, osb, 1);
    scan_A<<<512, 256, 0, stream>>>(fiz, Fsum, Ssum);
    scan_B<<<64, 256, 0, stream>>>(Fsum, Ssum, cst);
    scan_C<<<512, 256, 0, stream>>>(fiz, osb, cst, out, h1bf, hn + 32768, 1, 512);
}

// Round 7
// 635.178 us; speedup vs baseline: 8.3099x; 1.0964x over previous
//
#include <hip/hip_runtime.h>
#include <cstddef>
#include <cstdint>

#define Tn 512
#define Bn 32
#define Hn 512
static const size_t PLANE = 8388608; // Bn*Tn*Hn

typedef float f32x4 __attribute__((ext_vector_type(4)));
typedef __bf16 bf16x8 __attribute__((ext_vector_type(8)));
typedef _Float16 h2 __attribute__((ext_vector_type(2)));

__device__ __forceinline__ float sigm(float x) { return 1.0f / (1.0f + __expf(-x)); }
__device__ __forceinline__ float tanh_fast(float x) { return 2.0f / (1.0f + __expf(-2.0f * x)) - 1.0f; }
__device__ __forceinline__ unsigned short f2bf(float f) {
    unsigned int u = __float_as_uint(f);
    u += 0x7FFF + ((u >> 16) & 1);   // RNE
    return (unsigned short)(u >> 16);
}

// ---------------- conversion kernels ----------------

__global__ __launch_bounds__(256) void conv_x(const float* __restrict__ x,
                                              unsigned short* __restrict__ xbf) {
    const int i = blockIdx.x * 256 + threadIdx.x;  // 32*514*64
    const int c8 = i & 63;
    const int tp = (i >> 6) % 514;
    const int b  = (i >> 6) / 514;
    unsigned short v[8];
    if (tp == 0 || tp == 513) {
#pragma unroll
        for (int j = 0; j < 8; ++j) v[j] = 0;
    } else {
        const float* s = x + ((size_t)(tp - 1) * Bn + b) * 512 + c8 * 8;
#pragma unroll
        for (int j = 0; j < 8; ++j) v[j] = f2bf(s[j]);
    }
    unsigned short* d = xbf + ((size_t)b * 514 + tp) * 512 + c8 * 8;
    *(uint4*)d = *(const uint4*)v;
}

// both weight tensors: [dir][g][o][c][tap] fp32 -> [dir][m'=o*4+g][k'=tap*Cin+c] bf16
__global__ __launch_bounds__(256) void conv_w2(const float* __restrict__ w0,
                                               const float* __restrict__ w1,
                                               unsigned short* __restrict__ w0bf,
                                               unsigned short* __restrict__ w1bf) {
    int i = blockIdx.x * 256 + threadIdx.x;   // 4194304 + 8388608
    const float* src;
    unsigned short* dst;
    int Cin;
    if (i < 4194304) { src = w0; dst = w0bf; Cin = 512; }
    else { i -= 4194304; src = w1; dst = w1bf; Cin = 1024; }
    const int K = 2 * Cin;
    const int dm2 = i / K;            // dir*2048 + m'
    const int kp = i - dm2 * K;
    const int dir = dm2 >> 11;
    const int mp = dm2 & 2047;
    const int o = mp >> 2;
    const int g = mp & 3;
    const int tap = (kp >= Cin) ? 1 : 0;
    const int c = kp - tap * Cin;
    dst[i] = f2bf(src[((((size_t)dir * 4 + g) * 512 + o) * Cin + c) * 2 + tap]);
}

__global__ __launch_bounds__(256) void zero_h1pad(unsigned short* __restrict__ h1bf) {
    const int i = blockIdx.x * 256 + threadIdx.x;  // 65536
    const int c = i & 1023;
    const int b = (i >> 10) & 31;
    const int tp = (i >> 15) ? 513 : 0;
    h1bf[((size_t)b * 514 + tp) * 1024 + c] = 0;
}

// ---------------- fused-dir bf16 MFMA gate GEMM + activation + chunk-scan epilogue ----
// grid (128 n-tiles, 32): blockIdx.y = dir*16 + mtile.
// C[m'=o*4+g][n=(b,t)]; fragment f32x4 = {z,f,o,i} of one (o,n).
// Epilogue: activations -> fiz/osb (fp16), plus per-chunk scan summaries (F,S).
template <int CIN>
__global__ __launch_bounds__(256) void gate_gemm_bf16(
    const unsigned short* __restrict__ Wbf,  // [2][2048][2*CIN], rows m'=o*4+g
    const unsigned short* __restrict__ Xbf,  // [32][514][CIN]
    const float* __restrict__ bias,          // [2][4][512]
    h2* __restrict__ fiz,                    // [2][16384][512]
    _Float16* __restrict__ osb,              // [2][16384][512]
    float* __restrict__ Fsum,                // [2][8][32][512]
    float* __restrict__ Ssum)                // [2][8][32][512]
{
    __shared__ __align__(16) unsigned char smem[32768];
    unsigned short* As = (unsigned short*)smem;            // [128][64] swizzled
    unsigned short* Bs = (unsigned short*)(smem + 16384);  // [128][64] swizzled

    const int tid = threadIdx.x;
    const int lane = tid & 63;
    const int wave = tid >> 6;
    const int n0 = blockIdx.x * 128;   // x fastest => XCD keyed by n-tile only
    const int dir = blockIdx.y >> 4;
    const int m0 = (blockIdx.y & 15) * 128;
    const int wm = (wave & 1) * 64;
    const int wn = (wave >> 1) * 64;

    const unsigned short* Wb = Wbf + (size_t)dir * 2048 * 2 * CIN;

    // ---- hoisted loader state ----
    const unsigned short* pA[4];
    const unsigned short* pB0[4];
    unsigned short* ldst[8];
#pragma unroll
    for (int r = 0; r < 4; ++r) {
        const int q = r * 256 + tid;
        const int row = q >> 3;
        const int j = q & 7;
        const int kk = j ^ ((row >> 1) & 7);   // XOR swizzle baked into fetch addr
        pA[r] = Wb + (size_t)(m0 + row) * (2 * CIN) + kk * 8;
        const int n = n0 + row;
        const int t = n & 511;
        const int b = n >> 9;
        const int tp0 = dir ? (513 - t) : t;
        pB0[r] = Xbf + ((size_t)b * 514 + tp0) * CIN + kk * 8;
        ldst[r] = As + (size_t)q * 8;
        ldst[r + 4] = Bs + (size_t)q * 8;
    }
    const int dstep = dir ? -CIN : CIN;  // tap=1 B shift (elements)

    // ---- hoisted LDS fragment offsets (elements) ----
    int offA[2][4], offB[2][4];
#pragma unroll
    for (int kh = 0; kh < 2; ++kh) {
        const int jr = (lane >> 4) + kh * 4;
#pragma unroll
        for (int f = 0; f < 4; ++f) {
            const int ma = wm + f * 16 + (lane & 15);
            offA[kh][f] = ma * 64 + (jr ^ ((ma >> 1) & 7)) * 8;
            const int nb = wn + f * 16 + (lane & 15);
            offB[kh][f] = nb * 64 + (jr ^ ((nb >> 1) & 7)) * 8;
        }
    }

    f32x4 acc[4][4] = {};

    auto mfma_stage = [&]() {
#pragma unroll
        for (int kh = 0; kh < 2; ++kh) {
            bf16x8 af[4], bfr[4];
#pragma unroll
            for (int f = 0; f < 4; ++f) {
                af[f] = *(const bf16x8*)&As[offA[kh][f]];
                bfr[f] = *(const bf16x8*)&Bs[offB[kh][f]];
            }
#pragma unroll
            for (int fm = 0; fm < 4; ++fm)
#pragma unroll
                for (int fn = 0; fn < 4; ++fn)
                    acc[fm][fn] = __builtin_amdgcn_mfma_f32_16x16x32_bf16(
                        af[fm], bfr[fn], acc[fm][fn], 0, 0, 0);
        }
    };

#define GL(P, D) __builtin_amdgcn_global_load_lds( \
        (const __attribute__((address_space(1))) unsigned int*)(P), \
        (__attribute__((address_space(3))) unsigned int*)(D), 16, 0, 0)

#pragma unroll
    for (int tap = 0; tap < 2; ++tap) {
        const unsigned short* a0 = pA[0] + tap * CIN;
        const unsigned short* a1 = pA[1] + tap * CIN;
        const unsigned short* a2 = pA[2] + tap * CIN;
        const unsigned short* a3 = pA[3] + tap * CIN;
        const unsigned short* b0 = pB0[0] + tap * dstep;
        const unsigned short* b1 = pB0[1] + tap * dstep;
        const unsigned short* b2 = pB0[2] + tap * dstep;
        const unsigned short* b3 = pB0[3] + tap * dstep;
#pragma unroll
        for (int s = 0; s < CIN / 64; ++s) {   // BK=64 steps
            GL(a0, ldst[0]); GL(a1, ldst[1]);
            GL(a2, ldst[2]); GL(a3, ldst[3]);
            GL(b0, ldst[4]); GL(b1, ldst[5]);
            GL(b2, ldst[6]); GL(b3, ldst[7]);
            __builtin_amdgcn_s_waitcnt(0);
            __syncthreads();
            mfma_stage();
            __syncthreads();
            a0 += 64; a1 += 64; a2 += 64; a3 += 64;
            b0 += 64; b1 += 64; b2 += 64; b3 += 64;
        }
    }
#undef GL

    // ---- fused activation epilogue ----
    const int q = lane >> 4;
    const int o0 = (blockIdx.y & 15) * 32;
    const float* bb = bias + dir * 2048;
    float Bz[4], Bf[4], Bo[4], Bi[4];
#pragma unroll
    for (int fm = 0; fm < 4; ++fm) {
        const int o = o0 + (wm >> 2) + fm * 4 + q;
        Bz[fm] = bb[o];
        Bf[fm] = bb[512 + o];
        Bo[fm] = bb[1024 + o];
        Bi[fm] = bb[1536 + o];
    }
    h2* Lfiz = (h2*)smem;                          // [128][36] rows 144B
    _Float16* Los = (_Float16*)(smem + 18432);     // [128][40] rows 80B
#pragma unroll
    for (int fm = 0; fm < 4; ++fm) {
        const int ol = (wm >> 2) + fm * 4 + q;
#pragma unroll
        for (int fn = 0; fn < 4; ++fn) {
            f32x4 v = acc[fm][fn];
            const float f  = sigm(v.y + Bf[fm]);
            const float iz = sigm(v.w + Bi[fm]) * tanh_fast(v.x + Bz[fm]);
            const float os = sigm(v.z + Bo[fm]);
            const int nl = wn + fn * 16 + (lane & 15);
            h2 p; p.x = (_Float16)f; p.y = (_Float16)iz;
            Lfiz[nl * 36 + ol] = p;
            Los[nl * 40 + ol] = (_Float16)os;
        }
    }
    __syncthreads();
    h2* fz = fiz + (size_t)dir * PLANE;
    _Float16* ob = osb + (size_t)dir * PLANE;
#pragma unroll
    for (int l = 0; l < 4; ++l) {
        const int idx = l * 256 + tid;
        const int row = idx >> 3;
        const int col = idx & 7;
        uint4 v = *(const uint4*)((const unsigned char*)smem + row * 144 + col * 16);
        ((uint4*)(fz + (size_t)(n0 + row) * 512 + o0))[col] = v;
    }
#pragma unroll
    for (int l = 0; l < 2; ++l) {
        const int idx = l * 256 + tid;
        const int row = idx >> 2;
        const int col = idx & 3;
        uint4 v = *(const uint4*)((const unsigned char*)smem + 18432 + row * 80 + col * 16);
        ((uint4*)(ob + (size_t)(n0 + row) * 512 + o0))[col] = v;
    }
    // ---- per-chunk scan summaries (replaces scan_A) ----
    if (tid < 64) {
        const int ol = tid & 31;
        const int ch = tid >> 5;      // 2 chunks of 64 t per n-tile
        float F = 1.0f, S = 0.0f;
#pragma unroll
        for (int tt = 0; tt < 64; ++tt) {
            const h2 v = Lfiz[(ch * 64 + tt) * 36 + ol];
            const float f = (float)v.x;
            F *= f;
            S = f * S + (float)v.y;
        }
        const int b = n0 >> 9;
        const int chg = ((n0 & 511) >> 6) + ch;
        const int o = o0 + ol;
        const int sidx = dir * 131072 + chg * 16384 + b * 512 + o;
        Fsum[sidx] = F;
        Ssum[sidx] = S;
    }
}

// ---------------- scan kernels ----------------

__global__ __launch_bounds__(256) void scan_B(
    const float* __restrict__ Fsum, const float* __restrict__ Ssum,
    float* __restrict__ cstart)
{
    const int i = blockIdx.x * 256 + threadIdx.x;  // 32768 = 2 dir * 16384
    const int base = (i >> 14) * 131072 + (i & 16383);
    float c = 0.0f;
    for (int ch = 0; ch < 8; ++ch) {
        cstart[base + ch * 16384] = c;
        c = Fsum[base + ch * 16384] * c + Ssum[base + ch * 16384];
    }
}

__global__ __launch_bounds__(256) void scan_C(
    const h2* __restrict__ fiz, const _Float16* __restrict__ osb,
    const float* __restrict__ cstart, float* __restrict__ out,
    unsigned short* __restrict__ h1bf,
    float* __restrict__ hn, int isLayer2)
{
    const int idx = blockIdx.x * 256 + threadIdx.x;  // 262144 = 2 dir * 131072
    const int dir = idx >> 17;
    const int rem = idx & 131071;
    const int o = rem & 511;
    const int b = (rem >> 9) & 31;
    const int chunk = rem >> 14;
    const int dirH = dir * 512;
    float c = cstart[idx];
    const h2* fz = fiz + (size_t)dir * PLANE;
    const _Float16* ob = osb + (size_t)dir * PLANE;
    const int tbase = chunk * 64;
    for (int tt = 0; tt < 64; ++tt) {
        const int t = tbase + tt;
        const size_t idxg = ((size_t)(b * 512 + t)) * 512 + o;
        const h2 v = fz[idxg];
        const float f = (float)v.x;
        const float iz = (float)v.y;
        const float os = (float)ob[idxg];
        c = f * c + iz;
        const float outv = os * c;
        if (isLayer2) {
            out[((size_t)t * Bn + b) * 1024 + dirH + o] = outv;
        } else {
            h1bf[((size_t)b * 514 + (t + 1)) * 1024 + dirH + o] = f2bf(outv);
        }
        const bool isLast = (dir == 0) ? (t == Tn - 2) : (t == 0);
        if (isLast) hn[(size_t)b * 1024 + dirH + o] = outv;
    }
}

extern "C" void kernel_launch(void* const* d_in, const int* in_sizes, int n_in,
                              void* d_out, int out_size, void* d_ws, size_t ws_size,
                              hipStream_t stream) {
    const float* x  = (const float*)d_in[0];
    const float* w0 = (const float*)d_in[1];
    const float* b0 = (const float*)d_in[2];
    const float* w1 = (const float*)d_in[3];
    const float* b1 = (const float*)d_in[4];
    float* out = (float*)d_out;
    float* ws = (float*)d_ws;

    h2* fiz        = (h2*)ws;                               // 2*PLANE h2 (16.7M f)
    _Float16* osb  = (_Float16*)(ws + 16777216);            // 2*PLANE half (8.4M f)
    float* Fsum    = ws + 16777216 + 8388608;               // 262144
    float* Ssum    = Fsum + 262144;
    float* cst     = Ssum + 262144;
    unsigned short* xbf  = (unsigned short*)(cst + 262144); // 32*514*512
    unsigned short* h1bf = xbf + (size_t)32 * 514 * 512;    // 32*514*1024
    unsigned short* w0bf = h1bf + (size_t)32 * 514 * 1024;  // 2*2048*1024
    unsigned short* w1bf = w0bf + (size_t)2 * 2048 * 1024;  // 2*2048*2048
    float* hn = out + 16777216;

    conv_x<<<4112, 256, 0, stream>>>(x, xbf);
    conv_w2<<<49152, 256, 0, stream>>>(w0, w1, w0bf, w1bf);
    zero_h1pad<<<256, 256, 0, stream>>>(h1bf);

    const dim3 gg(128, 32);  // x = n-tiles (fastest); y = dir*16 + mtile

    // ---- Layer 1 (both dirs fused) ----
    gate_gemm_bf16<512><<<gg, 256, 0, stream>>>(w0bf, xbf, b0, fiz, osb, Fsum, Ssum);
    scan_B<<<128, 256, 0, stream>>>(Fsum, Ssum, cst);
    scan_C<<<1024, 256, 0, stream>>>(fiz, osb, cst, out, h1bf, hn, 0);
    // ---- Layer 2 (both dirs fused) ----
    gate_gemm_bf16<1024><<<gg, 256, 0, stream>>>(w1bf, h1bf, b1, fiz, osb, Fsum, Ssum);
    scan_B<<<128, 256, 0, stream>>>(Fsum, Ssum, cst);
    scan_C<<<1024, 256, 0, stream>>>(fiz, osb, cst, out, h1bf, hn + 32768, 1);
}